// Round 1
// baseline (225.084 us; speedup 1.0000x reference)
//
#include <hip/hip_runtime.h>
#include <cstdint>
#include <cstddef>

// Problem constants
constexpr int NB = 32;     // batch
constexpr int NK = 64;     // trajectories per batch
constexpr int NT = 80;     // timesteps
constexpr int NC = 256;    // bev channels
constexpr int NH = 200;
constexpr int NW = 200;
constexpr int NHW = NH * NW;
constexpr int NBK = NB * NK;  // 2048

// ---------------------------------------------------------------------------
// Kernel 1: per-(b,k) prep — grid indices, progress, comfort
// ---------------------------------------------------------------------------
__global__ __launch_bounds__(128) void prep_kernel(
    const float* __restrict__ traj, const float* __restrict__ goals,
    int* __restrict__ ws_idx, float* __restrict__ out)
{
    const int bk = blockIdx.x;
    const int tid = threadIdx.x;
    __shared__ float tr[NT * 2];
    __shared__ float accn[NT - 2];

    const float* tp = traj + (size_t)bk * (NT * 2);
    for (int i = tid; i < NT * 2; i += 128) tr[i] = tp[i];
    __syncthreads();

    if (tid < NT) {
        float x = tr[2 * tid];
        float y = tr[2 * tid + 1];
        // ((x / 50 + 1) * 200) / 2 == (x/50 + 1) * 100 bit-exactly (binade shift)
        int gx = (int)((x / 50.0f + 1.0f) * 100.0f);  // trunc-toward-zero == astype(int32)
        int gy = (int)((y / 50.0f + 1.0f) * 100.0f);
        gx = min(max(gx, 0), NW - 1);
        gy = min(max(gy, 0), NH - 1);
        ws_idx[bk * NT + tid] = gy * NW + gx;
    }
    if (tid < NT - 2) {
        float ax = tr[2 * (tid + 2)]     - 2.0f * tr[2 * (tid + 1)]     + tr[2 * tid];
        float ay = tr[2 * (tid + 2) + 1] - 2.0f * tr[2 * (tid + 1) + 1] + tr[2 * tid + 1];
        accn[tid] = sqrtf(ax * ax + ay * ay);
    }
    __syncthreads();

    if (tid == 0) {
        float s = 0.0f;
        for (int i = 0; i < NT - 2; ++i) s += accn[i];
        float mean_acc = s / (float)(NT - 2);
        float comfort = 1.0f / (1.0f + mean_acc);

        float fx = tr[2 * (NT - 1)], fy = tr[2 * (NT - 1) + 1];
        float gxv = goals[bk * 2], gyv = goals[bk * 2 + 1];
        float dx = fx - gxv, dy = fy - gyv;
        float progress = 1.0f / (1.0f + sqrtf(dx * dx + dy * dy));

        out[NBK + bk]     = progress;   // output 1: progress
        out[3 * NBK + bk] = comfort;    // output 3: comfort
    }
}

// ---------------------------------------------------------------------------
// Kernel 2: per-(b,c) gather + mean over T.  One block owns one 160KB plane;
// all line-reuse is intra-block (L1/L2), no cross-block scheduling dependence.
// ---------------------------------------------------------------------------
__global__ __launch_bounds__(256) void gather_kernel(
    const float* __restrict__ bev, const int* __restrict__ ws_idx,
    float* __restrict__ ws_bev)
{
    const int blk = blockIdx.x;        // b*NC + c
    const int b = blk >> 8;
    const int c = blk & 255;
    const int tid = threadIdx.x;

    __shared__ int sidx[NK * NT];      // 5120 ints = 20KB
    const int* wi = ws_idx + b * (NK * NT);
    for (int i = tid; i < NK * NT; i += 256) sidx[i] = wi[i];
    __syncthreads();

    const float* plane = bev + ((size_t)b * NC + c) * NHW;
    const int k = tid >> 2;            // 64 trajectories, 4 lanes each
    const int l = tid & 3;
    const int* myidx = sidx + k * NT + l * 20;

    float s = 0.0f;
    #pragma unroll
    for (int i = 0; i < 20; ++i) s += plane[myidx[i]];

    // reduce the 4 adjacent lanes that share one k
    s += __shfl_xor(s, 1);
    s += __shfl_xor(s, 2);
    if (l == 0) ws_bev[((size_t)b * NK + k) * NC + c] = s * (1.0f / 80.0f);
}

// ---------------------------------------------------------------------------
// Kernel 3: per-(b,k) trajectory MLP + collision head + final scores
// ---------------------------------------------------------------------------
__global__ __launch_bounds__(128) void mlp_kernel(
    const float* __restrict__ traj,
    const float* __restrict__ fe_w1, const float* __restrict__ fe_b1,
    const float* __restrict__ fe_w2, const float* __restrict__ fe_b2,
    const float* __restrict__ ch_w1, const float* __restrict__ ch_b1,
    const float* __restrict__ ch_w2, const float* __restrict__ ch_b2,
    const float* __restrict__ ws_bev, float* __restrict__ out)
{
    const int bk = blockIdx.x;
    const int tid = threadIdx.x;

    __shared__ float tr[NT * 2];
    __shared__ float h_all[NT * 64];   // 20KB
    __shared__ float comb[384];

    const float* tp = traj + (size_t)bk * (NT * 2);
    for (int i = tid; i < NT * 2; i += 128) tr[i] = tp[i];

    // each thread owns output channel `tid` of fe_w2: keep its column in regs
    float w2c[64];
    #pragma unroll
    for (int j = 0; j < 64; ++j) w2c[j] = fe_w2[j * 128 + tid];
    __syncthreads();

    // hidden layer for all 80 timesteps
    for (int u = tid; u < NT * 64; u += 128) {
        int t = u >> 6, j = u & 63;
        float h = tr[2 * t] * fe_w1[j] + tr[2 * t + 1] * fe_w1[64 + j] + fe_b1[j];
        h_all[u] = fmaxf(h, 0.0f);
    }
    __syncthreads();

    // f_i(t) = relu(b2_i + sum_j h[t][j] * w2[j][i]); mean over t
    float facc = 0.0f;
    const float b2 = fe_b2[tid];
    for (int t = 0; t < NT; ++t) {
        const float* hh = h_all + t * 64;
        float f = b2;
        #pragma unroll
        for (int j = 0; j < 64; ++j) f += hh[j] * w2c[j];  // hh[j]: LDS broadcast
        facc += fmaxf(f, 0.0f);
    }
    comb[tid] = facc * (1.0f / 80.0f);

    // bev_avg part of combined
    comb[128 + tid]       = ws_bev[(size_t)bk * NC + tid];
    comb[128 + 128 + tid] = ws_bev[(size_t)bk * NC + 128 + tid];
    __syncthreads();

    // collision head: wave 0 (threads 0..63), one hidden unit per lane
    if (tid < 64) {
        float a = ch_b1[tid];
        for (int m = 0; m < 384; ++m) a += comb[m] * ch_w1[m * 64 + tid];
        float v = fmaxf(a, 0.0f) * ch_w2[tid];
        #pragma unroll
        for (int off = 32; off >= 1; off >>= 1) v += __shfl_xor(v, off);
        if (tid == 0) {
            float logit = v + ch_b2[0];
            float collision = 1.0f / (1.0f + expf(-logit));
            float progress = out[NBK + bk];
            float comfort  = out[3 * NBK + bk];
            out[bk]           = progress - 2.0f * collision + 0.5f * comfort;
            out[2 * NBK + bk] = collision;
        }
    }
}

// ---------------------------------------------------------------------------
extern "C" void kernel_launch(void* const* d_in, const int* in_sizes, int n_in,
                              void* d_out, int out_size, void* d_ws, size_t ws_size,
                              hipStream_t stream)
{
    const float* traj  = (const float*)d_in[0];
    const float* goals = (const float*)d_in[1];
    const float* bev   = (const float*)d_in[2];
    const float* fe_w1 = (const float*)d_in[3];
    const float* fe_b1 = (const float*)d_in[4];
    const float* fe_w2 = (const float*)d_in[5];
    const float* fe_b2 = (const float*)d_in[6];
    const float* ch_w1 = (const float*)d_in[7];
    const float* ch_b1 = (const float*)d_in[8];
    const float* ch_w2 = (const float*)d_in[9];
    const float* ch_b2 = (const float*)d_in[10];
    float* out = (float*)d_out;

    // workspace layout: [idx: 2048*80 int][bev_avg: 2048*256 f32]  (~2.75 MB)
    int*   ws_idx = (int*)d_ws;
    float* ws_bev = (float*)((char*)d_ws + (size_t)NBK * NT * sizeof(int));

    prep_kernel<<<NBK, 128, 0, stream>>>(traj, goals, ws_idx, out);
    gather_kernel<<<NB * NC, 256, 0, stream>>>(bev, ws_idx, ws_bev);
    mlp_kernel<<<NBK, 128, 0, stream>>>(traj, fe_w1, fe_b1, fe_w2, fe_b2,
                                        ch_w1, ch_b1, ch_w2, ch_b2, ws_bev, out);
}